// Round 1
// baseline (208.571 us; speedup 1.0000x reference)
//
#include <hip/hip_runtime.h>
#include <math.h>

#define D_IN 131072
#define H 512
#define G4 2048      // 4*H
#define OUTN 16384   // 128*128

// ---- output flat offsets ----
// g:          [0, 16384)
// step_size:  16384
// m_c:        16385
// h stack:    [16386, 16386+1024)   h0 @16386, h1 @16898
// c stack:    [17410, 17410+1024)   c0 @17410, c1 @17922
#define OFF_STEP 16384
#define OFF_MC   16385
#define OFF_H0   16386
#define OFF_H1   16898
#define OFF_C0   17410
#define OFF_C1   17922

__device__ __forceinline__ float sigmoidf_(float x) {
    return 1.0f / (1.0f + __expf(-x));
}

__device__ __forceinline__ float dot4(float4 a, float4 b) {
    return a.x*b.x + a.y*b.y + a.z*b.z + a.w*b.w;
}

// Kernel 1: gates1[r] = W_ih1[r,:] . grad + W_hh1[r,:] . hidden0 + b_ih1[r] + b_hh1[r]
// One 256-thread block per row r (2048 blocks). grad = concat(dL_dU, dL_dV).
__global__ __launch_bounds__(256) void k_gemv1(
    const float* __restrict__ U, const float* __restrict__ V,
    const float* __restrict__ Wih, const float* __restrict__ Whh,
    const float* __restrict__ bih, const float* __restrict__ bhh,
    const float* __restrict__ hidden, float* __restrict__ gates)
{
    const int r = blockIdx.x;
    const int t = threadIdx.x;
    const float4* __restrict__ Wrow = (const float4*)(Wih + (size_t)r * D_IN);
    const float4* __restrict__ U4 = (const float4*)U;
    const float4* __restrict__ V4 = (const float4*)V;
    float acc = 0.0f;
    // 131072 floats = 32768 float4; 256 threads -> 128 iters each
    #pragma unroll 4
    for (int idx = t; idx < 32768; idx += 256) {
        float4 w = Wrow[idx];
        float4 x = (idx < 16384) ? U4[idx] : V4[idx - 16384];
        acc += dot4(w, x);
    }
    // hidden-recurrent part: 512 floats = 128 float4, threads 0..127
    if (t < 128) {
        const float4* Wh4 = (const float4*)(Whh + (size_t)r * H);
        const float4* h4  = (const float4*)hidden;  // hidden[0] = first 512
        acc += dot4(Wh4[t], h4[t]);
    }
    // reduce: wave64 shuffle then LDS across 4 waves
    #pragma unroll
    for (int off = 32; off > 0; off >>= 1) acc += __shfl_down(acc, off);
    __shared__ float s[4];
    if ((t & 63) == 0) s[t >> 6] = acc;
    __syncthreads();
    if (t == 0) {
        gates[r] = s[0] + s[1] + s[2] + s[3] + bih[r] + bhh[r];
    }
}

// Kernel 2: layer-1 cell combine -> h0,c0 (ws + out), and m_c scalar
__global__ __launch_bounds__(512) void k_cell1(
    const float* __restrict__ gates, const float* __restrict__ cell_in,
    const float* __restrict__ W3, const float* __restrict__ b3,
    float* __restrict__ h0, float* __restrict__ c0, float* __restrict__ out)
{
    const int j = threadIdx.x;  // 512 threads
    float ig = sigmoidf_(gates[j]);
    float fg = sigmoidf_(gates[H + j]);
    float gg = tanhf(gates[2*H + j]);
    float og = sigmoidf_(gates[3*H + j]);
    float c  = fg * cell_in[j] + ig * gg;   // cell[0]
    float h  = og * tanhf(c);
    h0[j] = h;  c0[j] = c;
    out[OFF_H0 + j] = h;
    out[OFF_C0 + j] = c;
    // m_c = clip(2*clip(h0.W3 + b3, 0, 1), 0, 1)
    float p = h * W3[j];
    #pragma unroll
    for (int off = 32; off > 0; off >>= 1) p += __shfl_down(p, off);
    __shared__ float s[8];
    if ((j & 63) == 0) s[j >> 6] = p;
    __syncthreads();
    if (j == 0) {
        float v = s[0]+s[1]+s[2]+s[3]+s[4]+s[5]+s[6]+s[7] + b3[0];
        v = fminf(fmaxf(v, 0.0f), 1.0f);
        v = fminf(2.0f * v, 1.0f);
        out[OFF_MC] = v;
    }
}

// Kernel 3: gates2[r] = W_ih2[r,:].h0 + W_hh2[r,:].hidden1 + b_ih2[r] + b_hh2[r]
// one wave per row, 4 waves/block -> 512 blocks
__global__ __launch_bounds__(256) void k_gemv2(
    const float* __restrict__ Wih, const float* __restrict__ Whh,
    const float* __restrict__ bih, const float* __restrict__ bhh,
    const float* __restrict__ h0, const float* __restrict__ hidden,
    float* __restrict__ gates2)
{
    const int wave = (blockIdx.x * 256 + threadIdx.x) >> 6;
    const int lane = threadIdx.x & 63;
    if (wave >= G4) return;
    const float4* Wr = (const float4*)(Wih + (size_t)wave * H);
    const float4* Hr = (const float4*)(Whh + (size_t)wave * H);
    const float4* x4 = (const float4*)h0;
    const float4* y4 = (const float4*)(hidden + H);   // hidden[1]
    float acc = 0.0f;
    #pragma unroll
    for (int k = lane; k < 128; k += 64) {
        acc += dot4(Wr[k], x4[k]);
        acc += dot4(Hr[k], y4[k]);
    }
    #pragma unroll
    for (int off = 32; off > 0; off >>= 1) acc += __shfl_down(acc, off);
    if (lane == 0) gates2[wave] = acc + bih[wave] + bhh[wave];
}

// Kernel 4: layer-2 cell combine -> h1,c1 (ws + out), and step_size scalar
__global__ __launch_bounds__(512) void k_cell2(
    const float* __restrict__ gates2, const float* __restrict__ cell_in,
    const float* __restrict__ W2, const float* __restrict__ b2,
    float* __restrict__ h1, float* __restrict__ c1, float* __restrict__ out)
{
    const int j = threadIdx.x;
    float ig = sigmoidf_(gates2[j]);
    float fg = sigmoidf_(gates2[H + j]);
    float gg = tanhf(gates2[2*H + j]);
    float og = sigmoidf_(gates2[3*H + j]);
    float c  = fg * cell_in[H + j] + ig * gg;  // cell[1]
    float h  = og * tanhf(c);
    h1[j] = h;  c1[j] = c;
    out[OFF_H1 + j] = h;
    out[OFF_C1 + j] = c;
    float p = h * W2[j];
    #pragma unroll
    for (int off = 32; off > 0; off >>= 1) p += __shfl_down(p, off);
    __shared__ float s[8];
    if ((j & 63) == 0) s[j >> 6] = p;
    __syncthreads();
    if (j == 0) {
        float v = s[0]+s[1]+s[2]+s[3]+s[4]+s[5]+s[6]+s[7] + b2[0];
        v = fminf(fmaxf(v, 1e-7f), 0.005f);
        out[OFF_STEP] = v;
    }
}

// Kernel 5: g[r] = W1[r,:].h1 + b1[r]   (16384 rows), one wave per row
__global__ __launch_bounds__(256) void k_out_g(
    const float* __restrict__ W1, const float* __restrict__ b1,
    const float* __restrict__ h1, float* __restrict__ out)
{
    const int wave = (blockIdx.x * 256 + threadIdx.x) >> 6;
    const int lane = threadIdx.x & 63;
    if (wave >= OUTN) return;
    const float4* Wr = (const float4*)(W1 + (size_t)wave * H);
    const float4* x4 = (const float4*)h1;
    float acc = 0.0f;
    #pragma unroll
    for (int k = lane; k < 128; k += 64) {
        acc += dot4(Wr[k], x4[k]);
    }
    #pragma unroll
    for (int off = 32; off > 0; off >>= 1) acc += __shfl_down(acc, off);
    if (lane == 0) out[wave] = acc + b1[wave];
}

extern "C" void kernel_launch(void* const* d_in, const int* in_sizes, int n_in,
                              void* d_out, int out_size, void* d_ws, size_t ws_size,
                              hipStream_t stream) {
    const float* dL_dU  = (const float*)d_in[0];
    const float* dL_dV  = (const float*)d_in[1];
    const float* hidden = (const float*)d_in[2];
    const float* cell   = (const float*)d_in[3];
    const float* W_ih1  = (const float*)d_in[4];
    const float* W_hh1  = (const float*)d_in[5];
    const float* b_ih1  = (const float*)d_in[6];
    const float* b_hh1  = (const float*)d_in[7];
    const float* W_ih2  = (const float*)d_in[8];
    const float* W_hh2  = (const float*)d_in[9];
    const float* b_ih2  = (const float*)d_in[10];
    const float* b_hh2  = (const float*)d_in[11];
    const float* W1     = (const float*)d_in[12];
    const float* b1     = (const float*)d_in[13];
    const float* W2     = (const float*)d_in[14];
    const float* b2     = (const float*)d_in[15];
    const float* W3     = (const float*)d_in[16];
    const float* b3     = (const float*)d_in[17];

    float* out = (float*)d_out;
    float* ws  = (float*)d_ws;
    float* gates1 = ws;             // 2048
    float* h0     = ws + 2048;      // 512
    float* c0     = ws + 2560;      // 512
    float* gates2 = ws + 3072;      // 2048
    float* h1     = ws + 5120;      // 512
    float* c1     = ws + 5632;      // 512

    k_gemv1<<<G4, 256, 0, stream>>>(dL_dU, dL_dV, W_ih1, W_hh1, b_ih1, b_hh1,
                                    hidden, gates1);
    k_cell1<<<1, 512, 0, stream>>>(gates1, cell, W3, b3, h0, c0, out);
    k_gemv2<<<G4/4, 256, 0, stream>>>(W_ih2, W_hh2, b_ih2, b_hh2, h0, hidden, gates2);
    k_cell2<<<1, 512, 0, stream>>>(gates2, cell, W2, b2, h1, c1, out);
    k_out_g<<<OUTN/4, 256, 0, stream>>>(W1, b1, h1, out);
    (void)in_sizes; (void)n_in; (void)out_size; (void)ws_size;
}

// Round 2
// 206.860 us; speedup vs baseline: 1.0083x; 1.0083x over previous
//
#include <hip/hip_runtime.h>
#include <math.h>

#define D_IN 131072
#define H 512
#define G4 2048      // 4*H
#define OUTN 16384   // 128*128

// ---- output flat offsets ----
// g: [0,16384)  step:16384  m_c:16385  h0:@16386  h1:@16898  c0:@17410  c1:@17922
#define OFF_STEP 16384
#define OFF_MC   16385
#define OFF_H0   16386
#define OFF_H1   16898
#define OFF_C0   17410
#define OFF_C1   17922

__device__ __forceinline__ float sigmoidf_(float x) {
    return 1.0f / (1.0f + __expf(-x));
}

__device__ __forceinline__ float dot4(float4 a, float4 b) {
    return a.x*b.x + a.y*b.y + a.z*b.z + a.w*b.w;
}

// ---------------------------------------------------------------------------
// K1: gates1[r] = W_ih1[r,:].grad + W_hh1[r,:].hidden0 + b_ih1[r] + b_hh1[r]
// One 256-thread block per row (2048 blocks). grad = concat(dL_dU, dL_dV).
// ---------------------------------------------------------------------------
__global__ __launch_bounds__(256) void k_gemv1(
    const float* __restrict__ U, const float* __restrict__ V,
    const float* __restrict__ Wih, const float* __restrict__ Whh,
    const float* __restrict__ bih, const float* __restrict__ bhh,
    const float* __restrict__ hidden, float* __restrict__ gates)
{
    const int r = blockIdx.x;
    const int t = threadIdx.x;
    const float4* __restrict__ Wrow = (const float4*)(Wih + (size_t)r * D_IN);
    const float4* __restrict__ U4 = (const float4*)U;
    const float4* __restrict__ V4 = (const float4*)V;
    float acc = 0.0f;
    // first half: 16384 float4 vs U
    #pragma unroll 4
    for (int idx = t; idx < 16384; idx += 256) {
        acc += dot4(Wrow[idx], U4[idx]);
    }
    // second half: 16384 float4 vs V
    #pragma unroll 4
    for (int idx = t; idx < 16384; idx += 256) {
        acc += dot4(Wrow[idx + 16384], V4[idx]);
    }
    // hidden-recurrent part: 512 floats = 128 float4, threads 0..127
    if (t < 128) {
        const float4* Wh4 = (const float4*)(Whh + (size_t)r * H);
        const float4* h4  = (const float4*)hidden;  // hidden[0]
        acc += dot4(Wh4[t], h4[t]);
    }
    #pragma unroll
    for (int off = 32; off > 0; off >>= 1) acc += __shfl_down(acc, off);
    __shared__ float s[4];
    if ((t & 63) == 0) s[t >> 6] = acc;
    __syncthreads();
    if (t == 0) {
        gates[r] = s[0] + s[1] + s[2] + s[3] + bih[r] + bhh[r];
    }
}

// ---------------------------------------------------------------------------
// K2: fused cell1 + gemv2. 128 blocks x 1024 threads (16 waves = 16 rows).
// Every block recomputes h0 from gates1 into LDS (redundant, cheap); block 0
// additionally writes h0/c0 to out and computes m_c.
// ---------------------------------------------------------------------------
__global__ __launch_bounds__(1024) void k_l2fused(
    const float* __restrict__ gates1, const float* __restrict__ cell_in,
    const float* __restrict__ hidden,
    const float* __restrict__ Wih2, const float* __restrict__ Whh2,
    const float* __restrict__ bih2, const float* __restrict__ bhh2,
    const float* __restrict__ W3, const float* __restrict__ b3,
    float* __restrict__ gates2, float* __restrict__ out)
{
    __shared__ float h0s[H];
    __shared__ float red[16];
    const int tid = threadIdx.x;
    if (tid < H) {
        float ig = sigmoidf_(gates1[tid]);
        float fg = sigmoidf_(gates1[H + tid]);
        float gg = tanhf(gates1[2*H + tid]);
        float og = sigmoidf_(gates1[3*H + tid]);
        float c  = fg * cell_in[tid] + ig * gg;   // cell[0]
        float h  = og * tanhf(c);
        h0s[tid] = h;
        if (blockIdx.x == 0) {
            out[OFF_H0 + tid] = h;
            out[OFF_C0 + tid] = c;
        }
    }
    __syncthreads();
    const int wv = tid >> 6, lane = tid & 63;
    const int row = blockIdx.x * 16 + wv;
    const float4* __restrict__ Wr = (const float4*)(Wih2 + (size_t)row * H);
    const float4* __restrict__ Hr = (const float4*)(Whh2 + (size_t)row * H);
    const float4* h4 = (const float4*)h0s;
    const float4* __restrict__ y4 = (const float4*)(hidden + H);  // hidden[1]
    float acc = dot4(Wr[lane],      h4[lane])      + dot4(Hr[lane],      y4[lane])
              + dot4(Wr[lane + 64], h4[lane + 64]) + dot4(Hr[lane + 64], y4[lane + 64]);
    #pragma unroll
    for (int off = 32; off > 0; off >>= 1) acc += __shfl_down(acc, off);
    if (lane == 0) gates2[row] = acc + bih2[row] + bhh2[row];

    if (blockIdx.x == 0) {
        // m_c = clip(2*clip(h0.W3 + b3, 0, 1), 0, 1)
        float p = (tid < H) ? h0s[tid] * W3[tid] : 0.0f;
        #pragma unroll
        for (int off = 32; off > 0; off >>= 1) p += __shfl_down(p, off);
        if (lane == 0) red[wv] = p;
        __syncthreads();
        if (tid == 0) {
            float v = b3[0];
            #pragma unroll
            for (int i = 0; i < 16; ++i) v += red[i];
            v = fminf(fmaxf(v, 0.0f), 1.0f);
            out[OFF_MC] = fminf(2.0f * v, 1.0f);
        }
    }
}

// ---------------------------------------------------------------------------
// K3: fused cell2 + out_g. 1024 blocks x 1024 threads (16 waves = 16 rows).
// Every block recomputes h1 from gates2 into LDS; block 0 writes h1/c1 and
// step_size.
// ---------------------------------------------------------------------------
__global__ __launch_bounds__(1024) void k_l3fused(
    const float* __restrict__ gates2, const float* __restrict__ cell_in,
    const float* __restrict__ W1, const float* __restrict__ b1,
    const float* __restrict__ W2, const float* __restrict__ b2,
    float* __restrict__ out)
{
    __shared__ float h1s[H];
    __shared__ float red[16];
    const int tid = threadIdx.x;
    if (tid < H) {
        float ig = sigmoidf_(gates2[tid]);
        float fg = sigmoidf_(gates2[H + tid]);
        float gg = tanhf(gates2[2*H + tid]);
        float og = sigmoidf_(gates2[3*H + tid]);
        float c  = fg * cell_in[H + tid] + ig * gg;  // cell[1]
        float h  = og * tanhf(c);
        h1s[tid] = h;
        if (blockIdx.x == 0) {
            out[OFF_H1 + tid] = h;
            out[OFF_C1 + tid] = c;
        }
    }
    __syncthreads();
    const int wv = tid >> 6, lane = tid & 63;
    const int row = blockIdx.x * 16 + wv;
    const float4* __restrict__ Wr = (const float4*)(W1 + (size_t)row * H);
    const float4* h4 = (const float4*)h1s;
    float acc = dot4(Wr[lane], h4[lane]) + dot4(Wr[lane + 64], h4[lane + 64]);
    #pragma unroll
    for (int off = 32; off > 0; off >>= 1) acc += __shfl_down(acc, off);
    if (lane == 0) out[row] = acc + b1[row];

    if (blockIdx.x == 0) {
        float p = (tid < H) ? h1s[tid] * W2[tid] : 0.0f;
        #pragma unroll
        for (int off = 32; off > 0; off >>= 1) p += __shfl_down(p, off);
        if (lane == 0) red[wv] = p;
        __syncthreads();
        if (tid == 0) {
            float v = b2[0];
            #pragma unroll
            for (int i = 0; i < 16; ++i) v += red[i];
            out[OFF_STEP] = fminf(fmaxf(v, 1e-7f), 0.005f);
        }
    }
}

extern "C" void kernel_launch(void* const* d_in, const int* in_sizes, int n_in,
                              void* d_out, int out_size, void* d_ws, size_t ws_size,
                              hipStream_t stream) {
    const float* dL_dU  = (const float*)d_in[0];
    const float* dL_dV  = (const float*)d_in[1];
    const float* hidden = (const float*)d_in[2];
    const float* cell   = (const float*)d_in[3];
    const float* W_ih1  = (const float*)d_in[4];
    const float* W_hh1  = (const float*)d_in[5];
    const float* b_ih1  = (const float*)d_in[6];
    const float* b_hh1  = (const float*)d_in[7];
    const float* W_ih2  = (const float*)d_in[8];
    const float* W_hh2  = (const float*)d_in[9];
    const float* b_ih2  = (const float*)d_in[10];
    const float* b_hh2  = (const float*)d_in[11];
    const float* W1     = (const float*)d_in[12];
    const float* b1     = (const float*)d_in[13];
    const float* W2     = (const float*)d_in[14];
    const float* b2     = (const float*)d_in[15];
    const float* W3     = (const float*)d_in[16];
    const float* b3     = (const float*)d_in[17];

    float* out = (float*)d_out;
    float* ws  = (float*)d_ws;
    float* gates1 = ws;             // 2048
    float* gates2 = ws + 2048;      // 2048

    k_gemv1<<<G4, 256, 0, stream>>>(dL_dU, dL_dV, W_ih1, W_hh1, b_ih1, b_hh1,
                                    hidden, gates1);
    k_l2fused<<<G4/16, 1024, 0, stream>>>(gates1, cell, hidden,
                                          W_ih2, W_hh2, b_ih2, b_hh2,
                                          W3, b3, gates2, out);
    k_l3fused<<<OUTN/16, 1024, 0, stream>>>(gates2, cell, W1, b1, W2, b2, out);
    (void)in_sizes; (void)n_in; (void)out_size; (void)ws_size;
}